// Round 4
// baseline (304.886 us; speedup 1.0000x reference)
//
#include <hip/hip_runtime.h>
#include <math.h>

#define B_ 2
#define S_ 2048
#define E_ 1024
#define H_ 16
#define HD_ 64
#define LAMBDA_INIT 0.8f
#define EPS_ 1e-6f

typedef __attribute__((ext_vector_type(8))) short short8;   // 8 bf16 (4 VGPRs)
typedef __attribute__((ext_vector_type(4))) float floatx4;  // MFMA C/D

// exp(s*0.125) == exp2(s * 0.125*log2(e))
#define EXP2SCALE 0.18033688011112042f

__device__ __forceinline__ unsigned short f2bf(float f) {
  unsigned u = __float_as_uint(f);
  u += 0x7FFFu + ((u >> 16) & 1u);   // RNE
  return (unsigned short)(u >> 16);
}

__device__ __forceinline__ void gl_lds16(const void* g, void* l) {
  __builtin_amdgcn_global_load_lds((const __attribute__((address_space(1))) void*)g,
                                   (__attribute__((address_space(3))) void*)l,
                                   16, 0, 0);
}

// ---------------------------------------------------------------------------
// cast fp32 -> bf16, contiguous
// ---------------------------------------------------------------------------
__global__ __launch_bounds__(256) void cast_bf16(const float* __restrict__ in,
                                                 unsigned short* __restrict__ out,
                                                 int n4) {
  for (int i = blockIdx.x * 256 + threadIdx.x; i < n4; i += gridDim.x * 256) {
    float4 v = ((const float4*)in)[i];
    ushort4 w;
    w.x = f2bf(v.x); w.y = f2bf(v.y); w.z = f2bf(v.z); w.w = f2bf(v.w);
    ((ushort4*)out)[i] = w;
  }
}

// ---------------------------------------------------------------------------
// transpose + cast: in fp32 [R][C] -> out bf16 [C][R]
// ---------------------------------------------------------------------------
__global__ __launch_bounds__(256) void transpose_cast(const float* __restrict__ in,
                                                      unsigned short* __restrict__ out,
                                                      int R, int C) {
  __shared__ float tile[64][65];
  const int tid = threadIdx.x;
  const int c0 = blockIdx.x * 64;
  const int r0 = blockIdx.y * 64;
#pragma unroll
  for (int it = 0; it < 16; it++) {
    int e = tid + it * 256;
    int rr = e >> 6, cc = e & 63;
    tile[rr][cc] = in[(size_t)(r0 + rr) * C + c0 + cc];
  }
  __syncthreads();
#pragma unroll
  for (int it = 0; it < 16; it++) {
    int e = tid + it * 256;
    int rr = e >> 6, cc = e & 63;
    out[(size_t)(c0 + rr) * R + r0 + cc] = f2bf(tile[cc][rr]);
  }
}

// ---------------------------------------------------------------------------
// bf16 MFMA GEMM: C[M][N] = A[M][K] @ B[K][N], B given TRANSPOSED as Bt[N][K].
// 128x128 tile, BK=64, global_load_lds w=16, XOR chunk swizzle.
// ---------------------------------------------------------------------------
template <bool BF16OUT>
__global__ __launch_bounds__(256) void gemm_bt(const unsigned short* __restrict__ A,
                                               const unsigned short* __restrict__ Bt,
                                               void* __restrict__ C,
                                               int M, int N, int K) {
  __shared__ __align__(16) unsigned short As[128 * 64];
  __shared__ __align__(16) unsigned short Bs[128 * 64];
  const int tid = threadIdx.x;
  const int wave = tid >> 6, lane = tid & 63;
  const int lane15 = lane & 15, quad = lane >> 4;
  const int m0 = blockIdx.y * 128;
  const int n0 = blockIdx.x * 128;
  const int wm = (wave & 1) * 64, wn = (wave >> 1) * 64;

  floatx4 acc[4][4];
#pragma unroll
  for (int mi = 0; mi < 4; mi++)
#pragma unroll
    for (int ni = 0; ni < 4; ni++) acc[mi][ni] = (floatx4)0.0f;

  const int rs = wave * 32 + (lane >> 3);
  const int cph = lane & 7;

  for (int k0 = 0; k0 < K; k0 += 64) {
    __syncthreads();
#pragma unroll
    for (int j = 0; j < 4; j++) {
      int r = rs + j * 8;
      int cl = cph ^ (r & 7);
      gl_lds16(A + (size_t)(m0 + r) * K + k0 + cl * 8, &As[(wave * 32 + j * 8) * 64]);
    }
#pragma unroll
    for (int j = 0; j < 4; j++) {
      int r = rs + j * 8;
      int cl = cph ^ (r & 7);
      gl_lds16(Bt + (size_t)(n0 + r) * K + k0 + cl * 8, &Bs[(wave * 32 + j * 8) * 64]);
    }
    __syncthreads();

#pragma unroll
    for (int ks = 0; ks < 2; ks++) {
      short8 af[4], bf[4];
#pragma unroll
      for (int mi = 0; mi < 4; mi++) {
        int r = wm + mi * 16 + lane15;
        int phys = (ks * 4 + quad) ^ (r & 7);
        af[mi] = *(const short8*)(&As[r * 64 + phys * 8]);
      }
#pragma unroll
      for (int ni = 0; ni < 4; ni++) {
        int r = wn + ni * 16 + lane15;
        int phys = (ks * 4 + quad) ^ (r & 7);
        bf[ni] = *(const short8*)(&Bs[r * 64 + phys * 8]);
      }
#pragma unroll
      for (int mi = 0; mi < 4; mi++)
#pragma unroll
        for (int ni = 0; ni < 4; ni++)
          acc[mi][ni] = __builtin_amdgcn_mfma_f32_16x16x32_bf16(af[mi], bf[ni],
                                                                acc[mi][ni], 0, 0, 0);
    }
  }

#pragma unroll
  for (int mi = 0; mi < 4; mi++)
#pragma unroll
    for (int ni = 0; ni < 4; ni++)
#pragma unroll
      for (int reg = 0; reg < 4; reg++) {
        int row = m0 + wm + mi * 16 + quad * 4 + reg;
        int col = n0 + wn + ni * 16 + lane15;
        float v = acc[mi][ni][reg];
        if (BF16OUT)
          ((unsigned short*)C)[(size_t)row * N + col] = f2bf(v);
        else
          ((float*)C)[(size_t)row * N + col] = v;
      }
}

// ---------------------------------------------------------------------------
// S^T-form MFMA flash differential attention.
// QK as mfma(A=K, B=Q): lane holds S^T[t=quad*4+reg][q=lane15] -> packed b64
// P writes to Ps[q][t]. PV as mfma(A=P, B=V^T) K=32. All staging via
// global_load_lds w=16, XOR chunk swizzle (c_phys = c_log ^ (row&7)), no pad.
// ---------------------------------------------------------------------------
__global__ __launch_bounds__(256) void flash_attn_mfma(
    const unsigned short* __restrict__ qkB, const unsigned short* __restrict__ vTB,
    const float* __restrict__ lq1, const float* __restrict__ lq2,
    const float* __restrict__ lk1, const float* __restrict__ lk2,
    const float* __restrict__ norm_w, float* __restrict__ out_n) {
  __shared__ __align__(16) unsigned short Qs[64 * 64];
  __shared__ __align__(16) unsigned short Ks[64 * 64];
  __shared__ __align__(16) unsigned short Vt[64 * 64];
  __shared__ __align__(16) unsigned short Ps[64 * 64];

  const int tid = threadIdx.x;
  const int wave = tid >> 6, lane = tid & 63;
  const int lane15 = lane & 15, quad = lane >> 4;
  const int m7 = lane15 & 7;
  const int bid = blockIdx.x;          // 1024 = B*H*32
  const int qt = bid & 31;
  const int h = (bid >> 5) & 15;
  const int b = bid >> 9;
  const int q0 = qt * 64;

  float a1 = 0.f, a2 = 0.f;
  for (int d = 0; d < HD_; d++) {
    a1 += lq1[d] * lk1[d];
    a2 += lq2[d] * lk2[d];
  }
  const float lam = __expf(a1) - __expf(a2) + LAMBDA_INIT;

  // staging constants: each wave DMA's 8-row chunks (8 lanes/row, 16B each)
  const int srow = lane >> 3;            // row within 8-row chunk
  const int scl = (lane & 7) ^ srow;     // logical chunk (XOR swizzle)

  // ---- stage Q ----
#pragma unroll
  for (int j = 0; j < 2; j++) {
    int r = wave * 16 + j * 8 + srow;
    gl_lds16(qkB + (size_t)(b * S_ + q0 + r) * 2048 + h * 64 + scl * 8,
             &Qs[(wave * 16 + j * 8) * 64]);
  }
  __syncthreads();

  const int myrow = wave * 16 + lane15;
  // Q as B-operand: B[n=q][k=d], chunk cl = s*4+quad
  const short8 bq0 = *(const short8*)(Qs + myrow * 64 + ((quad) ^ m7) * 8);
  const short8 bq1 = *(const short8*)(Qs + myrow * 64 + ((4 + quad) ^ m7) * 8);

  floatx4 accO[2][4];   // [stream][nd]; D[q=quad*4+reg][d=nd*16+lane15]
  float lsum[2] = {0.f, 0.f};
#pragma unroll
  for (int s = 0; s < 2; s++)
#pragma unroll
    for (int nd = 0; nd < 4; nd++) accO[s][nd] = (floatx4)0.0f;
  const floatx4 zero4 = (floatx4)0.0f;

  const size_t kgbase = (size_t)b * S_ * 2048 + 1024 + h * 64;
  const size_t vgbase = (size_t)h * 64 * 4096 + b * 2048;

  for (int t0 = 0; t0 < S_; t0 += 64) {
    __syncthreads();   // prior tile's frag reads done
#pragma unroll
    for (int j = 0; j < 2; j++) {
      int r = wave * 16 + j * 8 + srow;
      gl_lds16(qkB + kgbase + (size_t)(t0 + r) * 2048 + scl * 8,
               &Ks[(wave * 16 + j * 8) * 64]);
      gl_lds16(vTB + vgbase + (size_t)r * 4096 + t0 + scl * 8,
               &Vt[(wave * 16 + j * 8) * 64]);
    }
    __syncthreads();   // drains vmcnt: staged data visible

    // hoist V^T frags (shared by both streams): B[n=d][k=t]
    short8 vf[2][4];
#pragma unroll
    for (int ks = 0; ks < 2; ks++)
#pragma unroll
      for (int nd = 0; nd < 4; nd++)
        vf[ks][nd] = *(const short8*)(Vt + (nd * 16 + lane15) * 64 +
                                      ((ks * 4 + quad) ^ m7) * 8);

#pragma unroll
    for (int s = 0; s < 2; s++) {
      const short8 bq = s ? bq1 : bq0;
      floatx4 sv[4];
#pragma unroll
      for (int nb = 0; nb < 4; nb++) {
        const short8 ak = *(const short8*)(Ks + (nb * 16 + lane15) * 64 +
                                           ((s * 4 + quad) ^ m7) * 8);
        sv[nb] = __builtin_amdgcn_mfma_f32_16x16x32_bf16(ak, bq, zero4, 0, 0, 0);
      }
      // exp + pack: lane holds S^T[t=nb*16+quad*4+reg][q=lane15]
      float ls = 0.f;
#pragma unroll
      for (int nb = 0; nb < 4; nb++) {
        float p0 = exp2f(sv[nb][0] * EXP2SCALE);
        float p1 = exp2f(sv[nb][1] * EXP2SCALE);
        float p2 = exp2f(sv[nb][2] * EXP2SCALE);
        float p3 = exp2f(sv[nb][3] * EXP2SCALE);
        ls += (p0 + p1) + (p2 + p3);
        unsigned lo = (unsigned)f2bf(p0) | ((unsigned)f2bf(p1) << 16);
        unsigned hi = (unsigned)f2bf(p2) | ((unsigned)f2bf(p3) << 16);
        // write P[q=myrow][t = nb*16 + quad*4 .. +3] (one b64, wave-private row)
        int cl = nb * 2 + (quad >> 1);
        uint2* dst = (uint2*)(Ps + myrow * 64 + ((cl ^ m7) * 8) + (quad & 1) * 4);
        *dst = make_uint2(lo, hi);
      }
      lsum[s] += ls;
      // PV: A = P[q][t] (row myrow, k=quad*8+j), B = V^T frags
#pragma unroll
      for (int ks = 0; ks < 2; ks++) {
        const short8 ap = *(const short8*)(Ps + myrow * 64 + ((ks * 4 + quad) ^ m7) * 8);
#pragma unroll
        for (int nd = 0; nd < 4; nd++)
          accO[s][nd] = __builtin_amdgcn_mfma_f32_16x16x32_bf16(ap, vf[ks][nd],
                                                                accO[s][nd], 0, 0, 0);
      }
    }
  }

  // ---- epilogue ----
  // lsum: partial over t-subsets per quad; reduce across quads -> total for q=lane15
#pragma unroll
  for (int s = 0; s < 2; s++) {
    lsum[s] += __shfl_xor(lsum[s], 16, 64);
    lsum[s] += __shfl_xor(lsum[s], 32, 64);
  }
  const float* nw = norm_w + h * HD_;
  float nwv[4];
#pragma unroll
  for (int nd = 0; nd < 4; nd++) nwv[nd] = nw[nd * 16 + lane15];

#pragma unroll
  for (int r4 = 0; r4 < 4; r4++) {
    const int qloc = quad * 4 + r4;
    const float l1 = __shfl(lsum[0], qloc, 64);
    const float l2 = __shfl(lsum[1], qloc, 64);
    const float inv1 = 1.0f / l1;
    const float c2 = lam / l2;
    float o[4];
    float ss = 0.f;
#pragma unroll
    for (int nd = 0; nd < 4; nd++) {
      o[nd] = accO[0][nd][r4] * inv1 - accO[1][nd][r4] * c2;
      ss += o[nd] * o[nd];
    }
#pragma unroll
    for (int msk = 1; msk <= 8; msk <<= 1) ss += __shfl_xor(ss, msk, 64);
    const float rsc = (1.0f - LAMBDA_INIT) * rsqrtf(ss * (1.0f / 64.0f) + EPS_);
    const int trow = q0 + wave * 16 + qloc;
    float* dst = out_n + ((size_t)(b * H_ + h) * S_ + trow) * HD_;
#pragma unroll
    for (int nd = 0; nd < 4; nd++)
      dst[nd * 16 + lane15] = o[nd] * rsc * nwv[nd];
  }
}

// ---------------------------------------------------------------------------
// Reshape out_n [B,H,S,HD] fp32 -> hidden bf16 (reference cat/transpose/view)
// ---------------------------------------------------------------------------
__global__ __launch_bounds__(256) void reshape_out(const float* __restrict__ out_n,
                                                   unsigned short* __restrict__ hidden) {
  __shared__ float tile[64][65];
  const int tid = threadIdx.x;
  const int bi = blockIdx.x;  // B*H*32 = 1024
  const int tb = bi & 31;
  const int h = (bi >> 5) & 15;
  const int b = bi >> 9;
  const int t0 = tb * 64;
  const float* src = out_n + (((size_t)b * H_ + h) * S_ + t0) * HD_;
#pragma unroll
  for (int rr = 0; rr < 16; rr++) {
    int e = tid + rr * 256;
    tile[e >> 6][e & 63] = src[e];
  }
  __syncthreads();
  unsigned short* dst = hidden + (size_t)b * (S_ * E_) + h * S_ + t0;
#pragma unroll
  for (int rr = 0; rr < 16; rr++) {
    int e = tid + rr * 256;
    int d = e >> 6, tt = e & 63;
    dst[(size_t)d * (H_ * S_) + tt] = f2bf(tile[tt][d]);
  }
}

// ---------------------------------------------------------------------------
extern "C" void kernel_launch(void* const* d_in, const int* in_sizes, int n_in,
                              void* d_out, int out_size, void* d_ws, size_t ws_size,
                              hipStream_t stream) {
  const float* x = (const float*)d_in[0];
  const float* w_qkv = (const float*)d_in[1];
  const float* wo = (const float*)d_in[2];
  const float* lq1 = (const float*)d_in[3];
  const float* lq2 = (const float*)d_in[4];
  const float* lk1 = (const float*)d_in[5];
  const float* lk2 = (const float*)d_in[6];
  const float* norm_w = (const float*)d_in[7];
  float* out = (float*)d_out;

  unsigned short* xB = (unsigned short*)d_ws;             // 4096*1024
  unsigned short* WT = xB + (size_t)4096 * 1024;          // 3072*1024 (w_qkv^T)
  unsigned short* woT = WT + (size_t)3072 * 1024;         // 1024*1024
  unsigned short* qkB = woT + (size_t)1024 * 1024;        // 4096*2048
  unsigned short* vTB = qkB + (size_t)4096 * 2048;        // 1024*4096
  unsigned short* hidB = vTB + (size_t)1024 * 4096;       // 4096*1024
  float* out_n = (float*)(hidB + (size_t)4096 * 1024);    // 4 Mi floats

  // 0) bf16 casts / transposes of inputs
  cast_bf16<<<1024, 256, 0, stream>>>(x, xB, 4096 * 1024 / 4);
  transpose_cast<<<dim3(48, 16), 256, 0, stream>>>(w_qkv, WT, 1024, 3072);
  transpose_cast<<<dim3(16, 16), 256, 0, stream>>>(wo, woT, 1024, 1024);

  // 1a) q,k = x @ Wqk      -> qkB bf16 [4096][2048]
  gemm_bt<true><<<dim3(2048 / 128, 4096 / 128), 256, 0, stream>>>(
      xB, WT, (void*)qkB, 4096, 2048, 1024);
  // 1b) vT = Wv^T @ x^T    -> vTB bf16 [1024][4096]  (operand swap: free transpose)
  gemm_bt<true><<<dim3(4096 / 128, 1024 / 128), 256, 0, stream>>>(
      WT + (size_t)2048 * 1024, xB, (void*)vTB, 1024, 4096, 1024);

  // 2) MFMA differential flash attention + RMSNorm
  flash_attn_mfma<<<B_ * H_ * (S_ / 64), 256, 0, stream>>>(qkB, vTB, lq1, lq2, lk1,
                                                           lk2, norm_w, out_n);
  // 3) reshape per reference's cat/transpose/view -> bf16
  reshape_out<<<B_ * H_ * (S_ / 64), 256, 0, stream>>>(out_n, hidB);
  // 4) out = hidden @ wo (fp32 out)
  gemm_bt<false><<<dim3(1024 / 128, 4096 / 128), 256, 0, stream>>>(
      hidB, woT, (void*)out, 4096, 1024, 1024);
}